// Round 2
// baseline (177.447 us; speedup 1.0000x reference)
//
#include <hip/hip_runtime.h>
#include <hip/hip_bf16.h>

// VectorQuantizerEMA: N=16384, K=1024, D=256 (derived from in_sizes).
// Outputs (f32, concat): recons [N,D] | gamma [N,K] | new_centroids [K,D]

#define DECAY 0.95f
#define OMD   0.05f   // 1-DECAY
#define EPSV  1e-5f

// ---------------------------------------------------------------- csq
__global__ __launch_bounds__(64) void csq_kernel(const float* __restrict__ cent,
                                                 float* __restrict__ csq) {
  const int k = blockIdx.x;
  const int t = threadIdx.x;               // 64 threads, D=256 -> float4 each
  const float4 v = ((const float4*)(cent + (size_t)k * 256))[t];
  float s = v.x * v.x + v.y * v.y + v.z * v.z + v.w * v.w;
#pragma unroll
  for (int off = 32; off; off >>= 1) s += __shfl_down(s, off);
  if (t == 0) csq[k] = s;
}

// ---------------------------------------------------------------- dist GEMM
// dist[n,k] = csq[k] - 2 * dot(z[n,:], cent[k,:])   (z_sq dropped: softmax-invariant)
// Tile: BM=64 x BN=64, BD=32 depth chunks, 256 threads, 4x4 per thread.
#define BM 64
#define BN 64
#define BD 32

__global__ __launch_bounds__(256) void dist_gemm(const float* __restrict__ z,
                                                 const float* __restrict__ cent,
                                                 const float* __restrict__ csq,
                                                 float* __restrict__ dist,
                                                 int N, int K) {
  const int D = 256;
  __shared__ float Zs[BD][BM + 4];   // transposed: Zs[d][m], stride 68 keeps 16B align
  __shared__ float Cs[BD][BN + 4];

  const int tid = threadIdx.x;
  const int tx = tid & 15;           // 0..15 -> 4 cols each
  const int ty = tid >> 4;           // 0..15 -> 4 rows each
  const int row0 = blockIdx.x * BM;
  const int col0 = blockIdx.y * BN;

  // load mapping: 4 threads per row, 8 contiguous floats each
  const int lr = tid >> 2;           // 0..63
  const int ld = (tid & 3) * 8;      // 0,8,16,24

  const float* zp = z + (size_t)(row0 + lr) * D + ld;
  const float* cp = cent + (size_t)(col0 + lr) * D + ld;

  float acc[4][4] = {};

  for (int d0 = 0; d0 < D; d0 += BD) {
    float4 za = *(const float4*)(zp + d0);
    float4 zb = *(const float4*)(zp + d0 + 4);
    float4 ca = *(const float4*)(cp + d0);
    float4 cb = *(const float4*)(cp + d0 + 4);
    __syncthreads();   // previous iter's LDS reads done
    Zs[ld + 0][lr] = za.x; Zs[ld + 1][lr] = za.y;
    Zs[ld + 2][lr] = za.z; Zs[ld + 3][lr] = za.w;
    Zs[ld + 4][lr] = zb.x; Zs[ld + 5][lr] = zb.y;
    Zs[ld + 6][lr] = zb.z; Zs[ld + 7][lr] = zb.w;
    Cs[ld + 0][lr] = ca.x; Cs[ld + 1][lr] = ca.y;
    Cs[ld + 2][lr] = ca.z; Cs[ld + 3][lr] = ca.w;
    Cs[ld + 4][lr] = cb.x; Cs[ld + 5][lr] = cb.y;
    Cs[ld + 6][lr] = cb.z; Cs[ld + 7][lr] = cb.w;
    __syncthreads();
#pragma unroll
    for (int d = 0; d < BD; ++d) {
      const float4 zf = *(const float4*)&Zs[d][ty * 4];
      const float4 cf = *(const float4*)&Cs[d][tx * 4];
      acc[0][0] += zf.x * cf.x; acc[0][1] += zf.x * cf.y;
      acc[0][2] += zf.x * cf.z; acc[0][3] += zf.x * cf.w;
      acc[1][0] += zf.y * cf.x; acc[1][1] += zf.y * cf.y;
      acc[1][2] += zf.y * cf.z; acc[1][3] += zf.y * cf.w;
      acc[2][0] += zf.z * cf.x; acc[2][1] += zf.z * cf.y;
      acc[2][2] += zf.z * cf.z; acc[2][3] += zf.z * cf.w;
      acc[3][0] += zf.w * cf.x; acc[3][1] += zf.w * cf.y;
      acc[3][2] += zf.w * cf.z; acc[3][3] += zf.w * cf.w;
    }
  }

  const float c0 = csq[col0 + tx * 4 + 0];
  const float c1 = csq[col0 + tx * 4 + 1];
  const float c2 = csq[col0 + tx * 4 + 2];
  const float c3 = csq[col0 + tx * 4 + 3];
#pragma unroll
  for (int i = 0; i < 4; ++i) {
    const int r = row0 + ty * 4 + i;
    float4 o;
    o.x = c0 - 2.0f * acc[i][0];
    o.y = c1 - 2.0f * acc[i][1];
    o.z = c2 - 2.0f * acc[i][2];
    o.w = c3 - 2.0f * acc[i][3];
    *(float4*)&dist[(size_t)r * K + col0 + tx * 4] = o;
  }
}

// ---------------------------------------------------------------- row softmax + scatter
// In-place: gamma region holds dist on entry, gamma on exit.
__global__ __launch_bounds__(256) void row_softmax(const float* __restrict__ z,
                                                   const float* __restrict__ cent,
                                                   float* __restrict__ gamma,
                                                   float* __restrict__ recons,
                                                   float* __restrict__ dw,
                                                   float* __restrict__ counts,
                                                   int K) {
  const int n = blockIdx.x;
  const int t = threadIdx.x;                 // 256 threads, K=1024 -> float4 each
  float* row = gamma + (size_t)n * K;
  const float4 s = ((const float4*)row)[t];

  // local argmin (first-lowest-index on ties: strict < with ascending index scan)
  float mv = s.x; int mi = 4 * t;
  if (s.y < mv) { mv = s.y; mi = 4 * t + 1; }
  if (s.z < mv) { mv = s.z; mi = 4 * t + 2; }
  if (s.w < mv) { mv = s.w; mi = 4 * t + 3; }

#pragma unroll
  for (int off = 32; off; off >>= 1) {
    const float ov = __shfl_down(mv, off);
    const int   oi = __shfl_down(mi, off);
    if (ov < mv || (ov == mv && oi < mi)) { mv = ov; mi = oi; }
  }

  __shared__ float wv[4];
  __shared__ int   wi[4];
  __shared__ float fmin_s;
  __shared__ int   fidx_s;
  __shared__ float fsum_s;
  const int wave = t >> 6;
  if ((t & 63) == 0) { wv[wave] = mv; wi[wave] = mi; }
  __syncthreads();
  if (t == 0) {
    float bv = wv[0]; int bi = wi[0];
#pragma unroll
    for (int w = 1; w < 4; ++w)
      if (wv[w] < bv || (wv[w] == bv && wi[w] < bi)) { bv = wv[w]; bi = wi[w]; }
    fmin_s = bv; fidx_s = bi;
  }
  __syncthreads();

  const float bm = fmin_s;
  const float e0 = __expf(-5.0f * (s.x - bm));
  const float e1 = __expf(-5.0f * (s.y - bm));
  const float e2 = __expf(-5.0f * (s.z - bm));
  const float e3 = __expf(-5.0f * (s.w - bm));
  float ls = e0 + e1 + e2 + e3;
#pragma unroll
  for (int off = 32; off; off >>= 1) ls += __shfl_down(ls, off);
  if ((t & 63) == 0) wv[wave] = ls;
  __syncthreads();
  if (t == 0) fsum_s = wv[0] + wv[1] + wv[2] + wv[3];
  __syncthreads();

  const float inv = 1.0f / fsum_s;
  float4 g;
  g.x = e0 * inv; g.y = e1 * inv; g.z = e2 * inv; g.w = e3 * inv;
  ((float4*)row)[t] = g;

  const int idx = fidx_s;
  const float zv = z[(size_t)n * 256 + t];        // D=256, one elem/thread
  recons[(size_t)n * 256 + t] = cent[(size_t)idx * 256 + t];
  atomicAdd(&dw[(size_t)idx * 256 + t], zv);
  if (t == 0) atomicAdd(&counts[idx], 1.0f);
}

// ---------------------------------------------------------------- EMA finalize
__global__ __launch_bounds__(1024) void finalize_cs(const float* __restrict__ ema_cs,
                                                    const float* __restrict__ counts,
                                                    float* __restrict__ newcs, int K) {
  const int t = threadIdx.x;                       // 1024 threads == K
  const float v = ema_cs[t] * DECAY + OMD * counts[t];
  float sum = v;
#pragma unroll
  for (int off = 32; off; off >>= 1) sum += __shfl_down(sum, off);
  __shared__ float wsum[16];
  __shared__ float tot_s;
  if ((t & 63) == 0) wsum[t >> 6] = sum;
  __syncthreads();
  if (t == 0) {
    float a = 0.0f;
#pragma unroll
    for (int i = 0; i < 16; ++i) a += wsum[i];
    tot_s = a;
  }
  __syncthreads();
  const float n = tot_s;
  newcs[t] = (v + EPSV) / (n + (float)K * EPSV) * n;
}

__global__ __launch_bounds__(256) void finalize_centroids(const float* __restrict__ ema_w,
                                                          const float* __restrict__ dw,
                                                          const float* __restrict__ newcs,
                                                          float* __restrict__ outc,
                                                          int total) {
  const int i = blockIdx.x * 256 + threadIdx.x;
  if (i < total) {
    const int k = i >> 8;  // D=256
    outc[i] = (ema_w[i] * DECAY + OMD * dw[i]) / newcs[k];
  }
}

// ---------------------------------------------------------------- launch
extern "C" void kernel_launch(void* const* d_in, const int* in_sizes, int n_in,
                              void* d_out, int out_size, void* d_ws, size_t ws_size,
                              hipStream_t stream) {
  const float* z      = (const float*)d_in[0];
  const float* cent   = (const float*)d_in[1];
  const float* ema_w  = (const float*)d_in[2];
  const float* ema_cs = (const float*)d_in[3];

  const int K = in_sizes[3];            // 1024
  const int D = in_sizes[1] / K;        // 256
  const int N = in_sizes[0] / D;        // 16384

  float* out    = (float*)d_out;
  float* recons = out;                              // [N,D]
  float* gamma  = out + (size_t)N * D;              // [N,K] (holds dist, then gamma)
  float* outc   = gamma + (size_t)N * K;            // [K,D]

  float* dw     = (float*)d_ws;                     // [K,D]
  float* counts = dw + (size_t)K * D;               // [K]
  float* csq    = counts + K;                       // [K]
  float* newcs  = csq + K;                          // [K]

  // zero the accumulators (ws is poisoned, not re-zeroed between replays)
  hipMemsetAsync(dw, 0, (size_t)(K * D + K) * sizeof(float), stream);

  csq_kernel<<<K, 64, 0, stream>>>(cent, csq);

  dim3 grid(N / BM, K / BN);
  dist_gemm<<<grid, 256, 0, stream>>>(z, cent, csq, gamma, N, K);

  row_softmax<<<N, 256, 0, stream>>>(z, cent, gamma, recons, dw, counts, K);

  finalize_cs<<<1, K, 0, stream>>>(ema_cs, counts, newcs, K);

  finalize_centroids<<<(K * D + 255) / 256, 256, 0, stream>>>(ema_w, dw, newcs, outc, K * D);
}

// Round 3
// 95.337 us; speedup vs baseline: 1.8613x; 1.8613x over previous
//
#include <hip/hip_runtime.h>
#include <hip/hip_bf16.h>

// VectorQuantizerEMA: N=16384, K=1024, D=256.
// Outputs (f32, concat): recons [N,D] | gamma [N,K] | new_centroids [K,D]
// Strategy: split-bf16 MFMA distance GEMM (zh*ch + zh*cl + zl*ch), m97-style
// 128x128 tile with global_load_lds + XOR chunk swizzle (rule #21).

#define DECAY 0.95f
#define OMD   0.05f
#define EPSV  1e-5f

using f32x4  = __attribute__((ext_vector_type(4))) float;
using bf16x8 = __attribute__((ext_vector_type(8))) __bf16;

typedef __attribute__((address_space(3))) unsigned int       lds_uint;
typedef const __attribute__((address_space(1))) unsigned int glb_uint;

__device__ __forceinline__ void gload16(const void* g, const void* l) {
  // CK pattern: flat->LDS offset via 32-bit truncation; dst is wave-uniform.
  __builtin_amdgcn_global_load_lds((glb_uint*)(unsigned long long)g,
                                   (lds_uint*)(unsigned int)(unsigned long long)l,
                                   16, 0, 0);
}

__device__ __forceinline__ unsigned short f2bf(float f) {
  unsigned int u = __float_as_uint(f);
  unsigned int r = (u + 0x7FFFu + ((u >> 16) & 1u)) >> 16;
  return (unsigned short)r;
}
__device__ __forceinline__ float bf2f(unsigned short s) {
  return __uint_as_float(((unsigned int)s) << 16);
}

// ---------------------------------------------------------------- hi/lo split
__global__ __launch_bounds__(256) void convert_hilo(const float* __restrict__ src,
                                                    unsigned short* __restrict__ hi,
                                                    unsigned short* __restrict__ lo,
                                                    int total8) {
  const int i = blockIdx.x * 256 + threadIdx.x;
  if (i >= total8) return;
  const float4 a = ((const float4*)src)[2 * i];
  const float4 b = ((const float4*)src)[2 * i + 1];
  float f[8] = {a.x, a.y, a.z, a.w, b.x, b.y, b.z, b.w};
  union { unsigned short u[8]; uint4 v; } H, L;
#pragma unroll
  for (int j = 0; j < 8; ++j) {
    H.u[j] = f2bf(f[j]);
    L.u[j] = f2bf(f[j] - bf2f(H.u[j]));
  }
  ((uint4*)hi)[i] = H.v;
  ((uint4*)lo)[i] = L.v;
}

// ---------------------------------------------------------------- csq (fp32)
__global__ __launch_bounds__(64) void csq_kernel(const float* __restrict__ cent,
                                                 float* __restrict__ csq) {
  const int k = blockIdx.x;
  const int t = threadIdx.x;
  const float4 v = ((const float4*)(cent + (size_t)k * 256))[t];
  float s = v.x * v.x + v.y * v.y + v.z * v.z + v.w * v.w;
#pragma unroll
  for (int off = 32; off; off >>= 1) s += __shfl_down(s, off);
  if (t == 0) csq[k] = s;
}

// ---------------------------------------------------------------- MFMA dist GEMM
// dist[n,k] = csq[k] - 2*dot(z[n],cent[k]);  128x128 tile, 4 waves 2x2, BK=64.
__global__ __launch_bounds__(256, 2) void dist_gemm_mfma(
    const unsigned short* __restrict__ zh, const unsigned short* __restrict__ zl,
    const unsigned short* __restrict__ ch, const unsigned short* __restrict__ cl,
    const float* __restrict__ csq, float* __restrict__ dist) {
  __shared__ unsigned short lds[4][128 * 64];  // Ah Al Bh Bl, 16 KB each

  const int tid  = threadIdx.x;
  const int lane = tid & 63;
  const int w    = tid >> 6;

  // XCD-bijective swizzle: nwg=1024 divisible by 8.
  const int bid = blockIdx.x;
  const int lin = (bid & 7) * 128 + (bid >> 3);
  const int m0  = (lin >> 3) * 128;   // z row block
  const int n0  = (lin & 7) * 128;    // centroid col block

  const int wm0 = (w >> 1) * 64;
  const int wn0 = (w & 1) * 64;

  f32x4 acc[4][4];
#pragma unroll
  for (int i = 0; i < 4; ++i)
#pragma unroll
    for (int j = 0; j < 4; ++j) acc[i][j] = (f32x4){0.f, 0.f, 0.f, 0.f};

  const int srow = lane >> 3;  // 0..7 within an 8-row staging group
  const int scb  = lane & 7;   // landing chunk slot

  for (int d0 = 0; d0 < 256; d0 += 64) {
    __syncthreads();
#pragma unroll
    for (int j = 0; j < 4; ++j) {
      const int r0    = w * 32 + j * 8;
      const int row   = r0 + srow;
      const int chunk = scb ^ (row & 7);          // inverse-swizzled source
      const size_t go = (size_t)(d0 + chunk * 8); // depth element offset
      gload16(zh + (size_t)(m0 + row) * 256 + go, &lds[0][r0 * 64]);
      gload16(zl + (size_t)(m0 + row) * 256 + go, &lds[1][r0 * 64]);
      gload16(ch + (size_t)(n0 + row) * 256 + go, &lds[2][r0 * 64]);
      gload16(cl + (size_t)(n0 + row) * 256 + go, &lds[3][r0 * 64]);
    }
    __syncthreads();
#pragma unroll
    for (int s = 0; s < 2; ++s) {
      bf16x8 ah[4], al[4], bh[4], bl[4];
      const int kg = s * 4 + (lane >> 4);  // depth chunk index 0..7
#pragma unroll
      for (int f = 0; f < 4; ++f) {
        const int ra = wm0 + f * 16 + (lane & 15);
        const int ca = kg ^ (ra & 7);               // swizzled read
        ah[f] = *(const bf16x8*)&lds[0][ra * 64 + ca * 8];
        al[f] = *(const bf16x8*)&lds[1][ra * 64 + ca * 8];
        const int rb = wn0 + f * 16 + (lane & 15);
        const int cb = kg ^ (rb & 7);
        bh[f] = *(const bf16x8*)&lds[2][rb * 64 + cb * 8];
        bl[f] = *(const bf16x8*)&lds[3][rb * 64 + cb * 8];
      }
#pragma unroll
      for (int fm = 0; fm < 4; ++fm)
#pragma unroll
        for (int fn = 0; fn < 4; ++fn) {
          acc[fm][fn] = __builtin_amdgcn_mfma_f32_16x16x32_bf16(ah[fm], bh[fn], acc[fm][fn], 0, 0, 0);
          acc[fm][fn] = __builtin_amdgcn_mfma_f32_16x16x32_bf16(ah[fm], bl[fn], acc[fm][fn], 0, 0, 0);
          acc[fm][fn] = __builtin_amdgcn_mfma_f32_16x16x32_bf16(al[fm], bh[fn], acc[fm][fn], 0, 0, 0);
        }
    }
  }

#pragma unroll
  for (int fn = 0; fn < 4; ++fn) {
    const int col = n0 + wn0 + fn * 16 + (lane & 15);
    const float cq = csq[col];
#pragma unroll
    for (int fm = 0; fm < 4; ++fm) {
      const int row = m0 + wm0 + fm * 16 + ((lane >> 4) << 2);
#pragma unroll
      for (int r = 0; r < 4; ++r)
        dist[(size_t)(row + r) * 1024 + col] = cq - 2.0f * acc[fm][fn][r];
    }
  }
}

// ---------------------------------------------------------------- row softmax + scatter
__global__ __launch_bounds__(256) void row_softmax(const float* __restrict__ z,
                                                   const float* __restrict__ cent,
                                                   float* __restrict__ gamma,
                                                   float* __restrict__ recons,
                                                   float* __restrict__ dw,
                                                   float* __restrict__ counts,
                                                   int K) {
  const int n = blockIdx.x;
  const int t = threadIdx.x;
  float* row = gamma + (size_t)n * K;
  const float4 s = ((const float4*)row)[t];

  float mv = s.x; int mi = 4 * t;
  if (s.y < mv) { mv = s.y; mi = 4 * t + 1; }
  if (s.z < mv) { mv = s.z; mi = 4 * t + 2; }
  if (s.w < mv) { mv = s.w; mi = 4 * t + 3; }

#pragma unroll
  for (int off = 32; off; off >>= 1) {
    const float ov = __shfl_down(mv, off);
    const int   oi = __shfl_down(mi, off);
    if (ov < mv || (ov == mv && oi < mi)) { mv = ov; mi = oi; }
  }

  __shared__ float wv[4];
  __shared__ int   wi[4];
  __shared__ float fmin_s;
  __shared__ int   fidx_s;
  __shared__ float fsum_s;
  const int wave = t >> 6;
  if ((t & 63) == 0) { wv[wave] = mv; wi[wave] = mi; }
  __syncthreads();
  if (t == 0) {
    float bv = wv[0]; int bi = wi[0];
#pragma unroll
    for (int wq = 1; wq < 4; ++wq)
      if (wv[wq] < bv || (wv[wq] == bv && wi[wq] < bi)) { bv = wv[wq]; bi = wi[wq]; }
    fmin_s = bv; fidx_s = bi;
  }
  __syncthreads();

  const float bm = fmin_s;
  const float e0 = __expf(-5.0f * (s.x - bm));
  const float e1 = __expf(-5.0f * (s.y - bm));
  const float e2 = __expf(-5.0f * (s.z - bm));
  const float e3 = __expf(-5.0f * (s.w - bm));
  float ls = e0 + e1 + e2 + e3;
#pragma unroll
  for (int off = 32; off; off >>= 1) ls += __shfl_down(ls, off);
  if ((t & 63) == 0) wv[wave] = ls;
  __syncthreads();
  if (t == 0) fsum_s = wv[0] + wv[1] + wv[2] + wv[3];
  __syncthreads();

  const float inv = 1.0f / fsum_s;
  float4 g;
  g.x = e0 * inv; g.y = e1 * inv; g.z = e2 * inv; g.w = e3 * inv;
  ((float4*)row)[t] = g;

  const int idx = fidx_s;
  const float zv = z[(size_t)n * 256 + t];
  recons[(size_t)n * 256 + t] = cent[(size_t)idx * 256 + t];
  atomicAdd(&dw[(size_t)idx * 256 + t], zv);
  if (t == 0) atomicAdd(&counts[idx], 1.0f);
}

// ---------------------------------------------------------------- EMA finalize
__global__ __launch_bounds__(1024) void finalize_cs(const float* __restrict__ ema_cs,
                                                    const float* __restrict__ counts,
                                                    float* __restrict__ newcs, int K) {
  const int t = threadIdx.x;
  const float v = ema_cs[t] * DECAY + OMD * counts[t];
  float sum = v;
#pragma unroll
  for (int off = 32; off; off >>= 1) sum += __shfl_down(sum, off);
  __shared__ float wsum[16];
  __shared__ float tot_s;
  if ((t & 63) == 0) wsum[t >> 6] = sum;
  __syncthreads();
  if (t == 0) {
    float a = 0.0f;
#pragma unroll
    for (int i = 0; i < 16; ++i) a += wsum[i];
    tot_s = a;
  }
  __syncthreads();
  const float n = tot_s;
  newcs[t] = (v + EPSV) / (n + (float)K * EPSV) * n;
}

__global__ __launch_bounds__(256) void finalize_centroids(const float* __restrict__ ema_w,
                                                          const float* __restrict__ dw,
                                                          const float* __restrict__ newcs,
                                                          float* __restrict__ outc,
                                                          int total) {
  const int i = blockIdx.x * 256 + threadIdx.x;
  if (i < total) {
    const int k = i >> 8;
    outc[i] = (ema_w[i] * DECAY + OMD * dw[i]) / newcs[k];
  }
}

// ---------------------------------------------------------------- launch
extern "C" void kernel_launch(void* const* d_in, const int* in_sizes, int n_in,
                              void* d_out, int out_size, void* d_ws, size_t ws_size,
                              hipStream_t stream) {
  const float* z      = (const float*)d_in[0];
  const float* cent   = (const float*)d_in[1];
  const float* ema_w  = (const float*)d_in[2];
  const float* ema_cs = (const float*)d_in[3];

  const int K = in_sizes[3];            // 1024
  const int D = in_sizes[1] / K;        // 256
  const int N = in_sizes[0] / D;        // 16384

  float* out    = (float*)d_out;
  float* recons = out;                              // [N,D]
  float* gamma  = out + (size_t)N * D;              // [N,K] (dist, then gamma)
  float* outc   = gamma + (size_t)N * K;            // [K,D]

  // hi/lo bf16 copies live in output regions that are overwritten later:
  unsigned short* zh = (unsigned short*)recons;     // N*D shorts
  unsigned short* zl = zh + (size_t)N * D;          // N*D shorts (fills recons exactly)
  unsigned short* chp = (unsigned short*)outc;      // K*D shorts
  unsigned short* clp = chp + (size_t)K * D;        // K*D shorts (fills outc exactly)

  float* dw     = (float*)d_ws;                     // [K,D]
  float* counts = dw + (size_t)K * D;               // [K]
  float* csq    = counts + K;                       // [K]
  float* newcs  = csq + K;                          // [K]

  hipMemsetAsync(dw, 0, (size_t)(K * D + K) * sizeof(float), stream);

  convert_hilo<<<(N * D / 8 + 255) / 256, 256, 0, stream>>>(z, zh, zl, N * D / 8);
  convert_hilo<<<(K * D / 8 + 255) / 256, 256, 0, stream>>>(cent, chp, clp, K * D / 8);

  csq_kernel<<<K, 64, 0, stream>>>(cent, csq);

  dist_gemm_mfma<<<(N / 128) * (K / 128), 256, 0, stream>>>(zh, zl, chp, clp, csq, gamma);

  row_softmax<<<N, 256, 0, stream>>>(z, cent, gamma, recons, dw, counts, K);

  finalize_cs<<<1, K, 0, stream>>>(ema_cs, counts, newcs, K);

  finalize_centroids<<<(K * D + 255) / 256, 256, 0, stream>>>(ema_w, dw, newcs, outc, K * D);
}